// Round 4
// baseline (443.776 us; speedup 1.0000x reference)
//
#include <hip/hip_runtime.h>
#include <math.h>

#define N_NODES 20000
#define N_EDGES 320000
#define E_TOT   (N_EDGES + N_NODES)
#define C_IN  256
#define C_HID 256
#define C_OUT 128
#define NEG_SLOPE 0.2f
#define MT 5   // M-tiles (16 rows each) per wave in the MFMA GEMM

typedef __attribute__((ext_vector_type(8))) short bf16x8;
typedef __attribute__((ext_vector_type(4))) float f32x4;

// ---- all scratch in module globals (ws_size unknown; globals are safe) ----
// split-bf16 canonical inputs (x = hi + lo, each bf16)
__device__ __align__(16) unsigned short c_xh[(size_t)N_NODES * C_IN];
__device__ __align__(16) unsigned short c_xl[(size_t)N_NODES * C_IN];
__device__ __align__(16) unsigned short c_W1h[C_IN * C_HID], c_W1l[C_IN * C_HID];
__device__ __align__(16) unsigned short c_W2h[C_HID * C_OUT], c_W2l[C_HID * C_OUT];
__device__ float c_as1f[C_HID], c_ad1f[C_HID], c_b1f[C_HID];
__device__ float c_as2f[C_OUT], c_ad2f[C_OUT], c_b2f[C_OUT];
__device__ __align__(16) float g_h1f[(size_t)N_NODES * C_HID];   // layer-1 h (fp32)
__device__ __align__(16) unsigned short g_g1h[(size_t)N_NODES * C_HID]; // relu(agg1) hi
__device__ __align__(16) unsigned short g_g1l[(size_t)N_NODES * C_HID]; // relu(agg1) lo
__device__ __align__(16) float g_h2f[(size_t)N_NODES * C_OUT];   // layer-2 h (fp32)
__device__ float g_alps[N_NODES];
__device__ float g_alpd[N_NODES];
__device__ int   g_deg[N_NODES];
__device__ int   g_rowstart[N_NODES + 1];
__device__ int   g_cursor[N_NODES];
__device__ int   g_srcidx[E_TOT];
__device__ int   g_is64;    // edge_index arrived as raw int64 words
__device__ int   g_isf32;   // float inputs arrived as raw fp32 words

__device__ __forceinline__ float bf2f(unsigned short b){
  unsigned int u = ((unsigned int)b) << 16;
  return __builtin_bit_cast(float, u);
}
__device__ __forceinline__ unsigned short f2bf(float f){
  unsigned int u = __builtin_bit_cast(unsigned int, f);
  u += 0x7fffu + ((u >> 16) & 1u);   // round-to-nearest-even
  return (unsigned short)(u >> 16);
}
__device__ __forceinline__ int clampi(int v){
  v = v < 0 ? 0 : v;
  return v >= N_NODES ? N_NODES - 1 : v;
}
__device__ __forceinline__ void edge_sd(const int* ei, int e, int& s, int& d){
  if (e < N_EDGES){
    if (g_is64){ s = ei[2 * e]; d = ei[2 * (N_EDGES + e)]; }
    else       { s = ei[e];     d = ei[N_EDGES + e]; }
    s = clampi(s); d = clampi(d);
  } else {
    s = d = e - N_EDGES;  // self-loop
  }
}

// ---------------- dtype / layout probes ----------------
__global__ void probe_k(const unsigned int* __restrict__ xw, const int* __restrict__ ei){
  if (threadIdx.x != 0 || blockIdx.x != 0) return;
  // bf16-packed data: low 16 bits of each word are a bf16 from N(0,1) -> exponent
  // field in narrow window (~256/256). fp32 data: low bits ~uniform (~48/256).
  int inwin = 0;
  for (int i = 0; i < 256; ++i){
    unsigned int e = (xw[i] >> 7) & 0xFFu;
    if (e >= 0x60u && e <= 0x8Fu) ++inwin;
  }
  g_isf32 = (inwin < 200) ? 1 : 0;
  // int64 edge_index: high words of values in [0,20000) are all zero
  int all0 = 1;
  for (int i = 0; i < 64; ++i)
    if (ei[2 * i + 1] != 0){ all0 = 0; break; }
  g_is64 = all0;
}

// ---------------- canonicalize float inputs to split-bf16 / fp32 ----------------
__global__ void cvt_x_k(const void* __restrict__ src){
  int i = blockIdx.x * blockDim.x + threadIdx.x;
  if (i >= N_NODES * C_IN) return;
  float f = g_isf32 ? ((const float*)src)[i] : bf2f(((const unsigned short*)src)[i]);
  unsigned short h = f2bf(f);
  c_xh[i] = h;
  c_xl[i] = f2bf(f - bf2f(h));
}

struct Ptrs { const void* p[8]; };

__global__ void cvt_w_k(Ptrs ps){
  // b: 0=W1 1=a_src1 2=a_dst1 3=b1 4=W2 5=a_src2 6=a_dst2 7=b2
  const int sizes[8] = {C_IN * C_HID, C_HID, C_HID, C_HID,
                        C_HID * C_OUT, C_OUT, C_OUT, C_OUT};
  int b = blockIdx.y;
  int i = blockIdx.x * blockDim.x + threadIdx.x;
  if (i >= sizes[b]) return;
  const void* s = ps.p[b];
  float f = g_isf32 ? ((const float*)s)[i] : bf2f(((const unsigned short*)s)[i]);
  if (b == 0){
    unsigned short h = f2bf(f);
    c_W1h[i] = h; c_W1l[i] = f2bf(f - bf2f(h));
  } else if (b == 4){
    unsigned short h = f2bf(f);
    c_W2h[i] = h; c_W2l[i] = f2bf(f - bf2f(h));
  } else {
    float* vd = (b == 1) ? c_as1f : (b == 2) ? c_ad1f : (b == 3) ? c_b1f
              : (b == 5) ? c_as2f : (b == 6) ? c_ad2f : c_b2f;
    vd[i] = f;
  }
}

// ---------------- graph preprocessing ----------------
__global__ void zero_k(){
  int i = blockIdx.x * blockDim.x + threadIdx.x;
  if (i < N_NODES) g_deg[i] = 0;
}

__global__ void count_k(const int* __restrict__ ei){
  int e = blockIdx.x * blockDim.x + threadIdx.x;
  if (e >= E_TOT) return;
  int s, d;
  edge_sd(ei, e, s, d);
  atomicAdd(&g_deg[d], 1);
}

__global__ void scan_k(){
  __shared__ int s[1024];
  __shared__ int carry;
  const int n = N_NODES;
  int t = threadIdx.x;
  if (t == 0) carry = 0;
  __syncthreads();
  for (int base = 0; base < n; base += 1024){
    int i = base + t;
    int v = (i < n) ? g_deg[i] : 0;
    s[t] = v;
    __syncthreads();
    for (int off = 1; off < 1024; off <<= 1){
      int x = (t >= off) ? s[t - off] : 0;
      __syncthreads();
      s[t] += x;
      __syncthreads();
    }
    if (i < n){
      int val = carry + (s[t] - v);   // exclusive prefix + running carry
      g_rowstart[i] = val;
      g_cursor[i]   = val;
    }
    __syncthreads();
    if (t == 0) carry += s[1023];
    __syncthreads();
  }
  if (t == 0) g_rowstart[n] = carry;
}

__global__ void scatter_k(const int* __restrict__ ei){
  int e = blockIdx.x * blockDim.x + threadIdx.x;
  if (e >= E_TOT) return;
  int s, d;
  edge_sd(ei, e, s, d);
  int pos = atomicAdd(&g_cursor[d], 1);
  g_srcidx[pos] = s;
}

// ---------------- split-bf16 MFMA GEMM: H(fp32) = X @ W, X=Xh+Xl, W=Wh+Wl ----------------
// acc += Ah*Bh + Ah*Bl + Al*Bh  (Al*Bl term ~2^-18, dropped)
// grid = (M/(16*MT), Nc/64), block = 256 (4 waves, each one 16-col strip); K=256 both layers
__global__ void gemm_k(int sel){
  const unsigned short* Xh = sel ? g_g1h : c_xh;
  const unsigned short* Xl = sel ? g_g1l : c_xl;
  const unsigned short* Wh = sel ? c_W2h : c_W1h;
  const unsigned short* Wl = sel ? c_W2l : c_W1l;
  float* H = sel ? g_h2f : g_h1f;
  const int K  = 256;
  const int Nc = sel ? C_OUT : C_HID;

  int wave = (int)(threadIdx.x >> 6);
  int lane = (int)(threadIdx.x & 63);
  int tn   = blockIdx.y * 4 + wave;
  int col  = tn * 16 + (lane & 15);
  int kgrp = lane >> 4;
  int mbase = blockIdx.x * (16 * MT);

  f32x4 acc[MT];
#pragma unroll
  for (int m = 0; m < MT; ++m) acc[m] = (f32x4){0.f, 0.f, 0.f, 0.f};

  for (int kt = 0; kt < K / 32; ++kt){
    int kbase = kt * 32 + kgrp * 8;
    bf16x8 bh, bl;
#pragma unroll
    for (int j = 0; j < 8; ++j){
      size_t wi = (size_t)(kbase + j) * Nc + col;
      bh[j] = (short)Wh[wi];
      bl[j] = (short)Wl[wi];
    }
#pragma unroll
    for (int m = 0; m < MT; ++m){
      size_t ai = (size_t)(mbase + m * 16 + (lane & 15)) * K + kbase;
      bf16x8 ah = *(const bf16x8*)(Xh + ai);
      bf16x8 al = *(const bf16x8*)(Xl + ai);
      acc[m] = __builtin_amdgcn_mfma_f32_16x16x32_bf16(ah, bh, acc[m], 0, 0, 0);
      acc[m] = __builtin_amdgcn_mfma_f32_16x16x32_bf16(ah, bl, acc[m], 0, 0, 0);
      acc[m] = __builtin_amdgcn_mfma_f32_16x16x32_bf16(al, bh, acc[m], 0, 0, 0);
    }
  }
  int r0 = kgrp * 4;
#pragma unroll
  for (int m = 0; m < MT; ++m)
#pragma unroll
    for (int i = 0; i < 4; ++i)
      H[(size_t)(mbase + m * 16 + r0 + i) * Nc + col] = acc[m][i];
}

// ---------------- per-node attention logits: alpha = h . a (fp32) ----------------
template<int F>
__global__ void alpha_k(int sel){
  const float* H    = sel ? g_h2f  : g_h1f;
  const float* av_s = sel ? c_as2f : c_as1f;
  const float* av_d = sel ? c_ad2f : c_ad1f;
  int wave = (int)(threadIdx.x >> 6);
  int lane = (int)(threadIdx.x & 63);
  int node = blockIdx.x * 4 + wave;
  const int PER = F / 64;
  float ss = 0.f, sd = 0.f;
#pragma unroll
  for (int j = 0; j < PER; ++j){
    int f = lane * PER + j;
    float h = H[(size_t)node * F + f];
    ss += h * av_s[f];
    sd += h * av_d[f];
  }
#pragma unroll
  for (int o = 32; o > 0; o >>= 1){
    ss += __shfl_xor(ss, o, 64);
    sd += __shfl_xor(sd, o, 64);
  }
  if (lane == 0){ g_alps[node] = ss; g_alpd[node] = sd; }
}

// ---------------- softmax + weighted aggregation, one block per dst node ----------------
// SEL=0: layer 1 -> relu, write split-bf16 g1.  SEL=1: layer 2 -> write fp32 OUT.
template<int F, int SEL>
__global__ void agg_k(float* OUT_ext){
  const float* H    = SEL ? g_h2f : g_h1f;
  const float* bias = SEL ? c_b2f : c_b1f;

  int n = blockIdx.x;
  int t = threadIdx.x;
  int i0 = g_rowstart[n], i1 = g_rowstart[n + 1];
  float adn = g_alpd[n];

  float m = -1e30f;
  for (int i = i0; i < i1; ++i){
    int s = g_srcidx[i];
    float e = g_alps[s] + adn;
    e = (e > 0.f) ? e : NEG_SLOPE * e;
    m = fmaxf(m, e);
  }
  float acc = 0.f, denom = 0.f;
  for (int i = i0; i < i1; ++i){
    int s = g_srcidx[i];
    float e = g_alps[s] + adn;
    e = (e > 0.f) ? e : NEG_SLOPE * e;
    float w = expf(e - m);
    denom += w;
    acc += w * H[(size_t)s * F + t];
  }
  float o = acc / denom + bias[t];
  if (SEL == 0){
    o = fmaxf(o, 0.f);                       // relu
    unsigned short h = f2bf(o);
    g_g1h[(size_t)n * F + t] = h;
    g_g1l[(size_t)n * F + t] = f2bf(o - bf2f(h));
  } else {
    OUT_ext[(size_t)n * F + t] = o;          // fp32 output
  }
}

extern "C" void kernel_launch(void* const* d_in, const int* in_sizes, int n_in,
                              void* d_out, int out_size, void* d_ws, size_t ws_size,
                              hipStream_t stream){
  (void)in_sizes; (void)n_in; (void)out_size; (void)d_ws; (void)ws_size;
  const void* x  = d_in[0];
  const int*  ei = (const int*)d_in[1];
  float* out = (float*)d_out;

  // probes + canonicalization (dtype is measured, not assumed)
  probe_k<<<1, 64, 0, stream>>>((const unsigned int*)x, ei);
  cvt_x_k<<<(N_NODES * C_IN + 255) / 256, 256, 0, stream>>>(x);
  Ptrs ps;
  ps.p[0] = d_in[2]; ps.p[1] = d_in[3]; ps.p[2] = d_in[4]; ps.p[3] = d_in[5];
  ps.p[4] = d_in[6]; ps.p[5] = d_in[7]; ps.p[6] = d_in[8]; ps.p[7] = d_in[9];
  cvt_w_k<<<dim3((C_IN * C_HID + 255) / 256, 8), 256, 0, stream>>>(ps);

  // graph preprocessing (rebuilt every call; no cross-call state)
  zero_k<<<(N_NODES + 255) / 256, 256, 0, stream>>>();
  count_k<<<(E_TOT + 255) / 256, 256, 0, stream>>>(ei);
  scan_k<<<1, 1024, 0, stream>>>();
  scatter_k<<<(E_TOT + 255) / 256, 256, 0, stream>>>(ei);

  // ---- layer 1 ----
  gemm_k<<<dim3(N_NODES / (16 * MT), C_HID / 64), 256, 0, stream>>>(0);
  alpha_k<C_HID><<<N_NODES / 4, 256, 0, stream>>>(0);
  agg_k<C_HID, 0><<<N_NODES, C_HID, 0, stream>>>(nullptr);

  // ---- layer 2 ----
  gemm_k<<<dim3(N_NODES / (16 * MT), C_OUT / 64), 256, 0, stream>>>(1);
  alpha_k<C_OUT><<<N_NODES / 4, 256, 0, stream>>>(1);
  agg_k<C_OUT, 1><<<N_NODES, C_OUT, 0, stream>>>(out);
}

// Round 5
// 349.821 us; speedup vs baseline: 1.2686x; 1.2686x over previous
//
#include <hip/hip_runtime.h>
#include <math.h>

#define N_NODES 20000
#define N_EDGES 320000
#define E_TOT   (N_EDGES + N_NODES)
#define C_IN  256
#define C_HID 256
#define C_OUT 128
#define NEG_SLOPE 0.2f
#define MT 5   // M-tiles (16 rows each) per wave in the MFMA GEMM

typedef __attribute__((ext_vector_type(8))) short bf16x8;
typedef __attribute__((ext_vector_type(4))) float f32x4;

// ---- all scratch in module globals (ws_size unknown; globals are safe) ----
__device__ __align__(16) unsigned short c_xh[(size_t)N_NODES * C_IN];   // x split hi
__device__ __align__(16) unsigned short c_xl[(size_t)N_NODES * C_IN];   // x split lo
// weights stored TRANSPOSED [n][k] so B-fragments are contiguous bf16x8 loads
__device__ __align__(16) unsigned short c_W1h[C_IN * C_HID], c_W1l[C_IN * C_HID];
__device__ __align__(16) unsigned short c_W2h[C_HID * C_OUT], c_W2l[C_HID * C_OUT];
__device__ float c_as1f[C_HID], c_ad1f[C_HID], c_b1f[C_HID];
__device__ float c_as2f[C_OUT], c_ad2f[C_OUT], c_b2f[C_OUT];
__device__ __align__(16) unsigned short g_h1b[(size_t)N_NODES * C_HID]; // h1 bf16
__device__ __align__(16) unsigned short g_g1h[(size_t)N_NODES * C_HID]; // relu(agg1) hi
__device__ __align__(16) unsigned short g_g1l[(size_t)N_NODES * C_HID]; // relu(agg1) lo
__device__ __align__(16) unsigned short g_h2b[(size_t)N_NODES * C_OUT]; // h2 bf16
__device__ float g_alps1[N_NODES], g_alpd1[N_NODES];
__device__ float g_alps2[N_NODES], g_alpd2[N_NODES];
__device__ float g_ew[E_TOT];          // per-edge softmax numerator exp(e)
__device__ int   g_deg[N_NODES];
__device__ int   g_rowstart[N_NODES + 1];
__device__ int   g_cursor[N_NODES];
__device__ int   g_srcidx[E_TOT];
__device__ int   g_dstslot[E_TOT];
__device__ int   g_bsum[20];
__device__ int   g_is64;    // edge_index arrived as raw int64 words
__device__ int   g_isf32;   // float inputs arrived as raw fp32 words

__device__ __forceinline__ float bf2f(unsigned short b){
  unsigned int u = ((unsigned int)b) << 16;
  return __builtin_bit_cast(float, u);
}
__device__ __forceinline__ unsigned short f2bf(float f){
  unsigned int u = __builtin_bit_cast(unsigned int, f);
  u += 0x7fffu + ((u >> 16) & 1u);   // round-to-nearest-even
  return (unsigned short)(u >> 16);
}
__device__ __forceinline__ int clampi(int v){
  v = v < 0 ? 0 : v;
  return v >= N_NODES ? N_NODES - 1 : v;
}
__device__ __forceinline__ void edge_sd(const int* ei, int e, int& s, int& d){
  if (e < N_EDGES){
    if (g_is64){ s = ei[2 * e]; d = ei[2 * (N_EDGES + e)]; }
    else       { s = ei[e];     d = ei[N_EDGES + e]; }
    s = clampi(s); d = clampi(d);
  } else {
    s = d = e - N_EDGES;  // self-loop
  }
}

// ---------------- dtype / layout probes ----------------
__global__ void probe_k(const unsigned int* __restrict__ xw, const int* __restrict__ ei){
  if (threadIdx.x != 0 || blockIdx.x != 0) return;
  int inwin = 0;
  for (int i = 0; i < 256; ++i){
    unsigned int e = (xw[i] >> 7) & 0xFFu;
    if (e >= 0x60u && e <= 0x8Fu) ++inwin;
  }
  g_isf32 = (inwin < 200) ? 1 : 0;   // fp32 low-mantissa bits ~uniform
  int all0 = 1;
  for (int i = 0; i < 64; ++i)
    if (ei[2 * i + 1] != 0){ all0 = 0; break; }
  g_is64 = all0;
}

// ---------------- canonicalize inputs ----------------
__global__ void cvt_x_k(const void* __restrict__ src){
  int i = blockIdx.x * blockDim.x + threadIdx.x;
  if (i >= N_NODES * C_IN) return;
  float f = g_isf32 ? ((const float*)src)[i] : bf2f(((const unsigned short*)src)[i]);
  unsigned short h = f2bf(f);
  c_xh[i] = h;
  c_xl[i] = f2bf(f - bf2f(h));
}

struct Ptrs { const void* p[8]; };

__global__ void cvt_w_k(Ptrs ps){
  // b: 0=W1 1=a_src1 2=a_dst1 3=b1 4=W2 5=a_src2 6=a_dst2 7=b2
  const int sizes[8] = {C_IN * C_HID, C_HID, C_HID, C_HID,
                        C_HID * C_OUT, C_OUT, C_OUT, C_OUT};
  int b = blockIdx.y;
  int i = blockIdx.x * blockDim.x + threadIdx.x;
  if (i >= sizes[b]) return;
  const void* s = ps.p[b];
  float f = g_isf32 ? ((const float*)s)[i] : bf2f(((const unsigned short*)s)[i]);
  if (b == 0){                           // W1 [256][256] -> transposed [n][k]
    int k = i / C_HID, n = i % C_HID;
    unsigned short h = f2bf(f);
    c_W1h[n * C_IN + k] = h;
    c_W1l[n * C_IN + k] = f2bf(f - bf2f(h));
  } else if (b == 4){                    // W2 [256][128] -> transposed [n][k]
    int k = i / C_OUT, n = i % C_OUT;
    unsigned short h = f2bf(f);
    c_W2h[n * C_HID + k] = h;
    c_W2l[n * C_HID + k] = f2bf(f - bf2f(h));
  } else {
    float* vd = (b == 1) ? c_as1f : (b == 2) ? c_ad1f : (b == 3) ? c_b1f
              : (b == 5) ? c_as2f : (b == 6) ? c_ad2f : c_b2f;
    vd[i] = f;
  }
}

// ---------------- graph preprocessing ----------------
__global__ void zero_k(){
  int i = blockIdx.x * blockDim.x + threadIdx.x;
  if (i < N_NODES){
    g_deg[i] = 0;
    g_alps1[i] = 0.f; g_alpd1[i] = 0.f;
    g_alps2[i] = 0.f; g_alpd2[i] = 0.f;
  }
}

__global__ void count_k(const int* __restrict__ ei){
  int e = blockIdx.x * blockDim.x + threadIdx.x;
  if (e >= E_TOT) return;
  int s, d;
  edge_sd(ei, e, s, d);
  atomicAdd(&g_deg[d], 1);
}

// two-phase multi-block exclusive scan of deg[20000]: 20 blocks x 1000
__global__ void scanA_k(){
  __shared__ int s[1024];
  int b = blockIdx.x, t = threadIdx.x;
  int i = b * 1000 + t;
  int v = (t < 1000) ? g_deg[i] : 0;
  s[t] = v;
  __syncthreads();
  for (int off = 1; off < 1024; off <<= 1){
    int x = (t >= off) ? s[t - off] : 0;
    __syncthreads();
    s[t] += x;
    __syncthreads();
  }
  if (t < 1000) g_rowstart[i] = s[t] - v;   // block-local exclusive
  if (t == 1023) g_bsum[b] = s[1023];
}

__global__ void scanC_k(){
  __shared__ int off;
  int b = blockIdx.x, t = threadIdx.x;
  if (t == 0){
    int o = 0;
    for (int j = 0; j < b; ++j) o += g_bsum[j];
    off = o;
  }
  __syncthreads();
  int i = b * 1000 + t;
  if (t < 1000){
    int val = g_rowstart[i] + off;
    g_rowstart[i] = val;
    g_cursor[i]   = val;
  }
  if (b == 0 && t == 0) g_rowstart[N_NODES] = E_TOT;
}

__global__ void scatter_k(const int* __restrict__ ei){
  int e = blockIdx.x * blockDim.x + threadIdx.x;
  if (e >= E_TOT) return;
  int s, d;
  edge_sd(ei, e, s, d);
  int pos = atomicAdd(&g_cursor[d], 1);
  g_srcidx[pos]  = s;
  g_dstslot[pos] = d;
}

// ---------------- split-bf16 MFMA GEMM + fused alpha epilogue ----------------
// H = X @ W (X=Xh+Xl, W=Wh+Wl; acc += Ah*Bh + Ah*Bl + Al*Bh).  h stored bf16.
// alpha_src/dst accumulated via 16-lane butterfly + atomicAdd (alps zeroed).
// grid = (M/80, Nc/64), block 256 (4 waves, each one 16-col strip); K=256.
__global__ void gemm_k(int sel){
  const unsigned short* Xh = sel ? g_g1h : c_xh;
  const unsigned short* Xl = sel ? g_g1l : c_xl;
  const unsigned short* Wh = sel ? c_W2h : c_W1h;   // [n][k]
  const unsigned short* Wl = sel ? c_W2l : c_W1l;
  unsigned short* Hb = sel ? g_h2b : g_h1b;
  float* alps = sel ? g_alps2 : g_alps1;
  float* alpd = sel ? g_alpd2 : g_alpd1;
  const float* aS = sel ? c_as2f : c_as1f;
  const float* aD = sel ? c_ad2f : c_ad1f;
  const int K  = 256;
  const int Nc = sel ? C_OUT : C_HID;

  int wave = (int)(threadIdx.x >> 6);
  int lane = (int)(threadIdx.x & 63);
  int col  = (blockIdx.y * 4 + wave) * 16 + (lane & 15);
  int kgrp = lane >> 4;
  int mbase = blockIdx.x * (16 * MT);

  f32x4 acc[MT];
#pragma unroll
  for (int m = 0; m < MT; ++m) acc[m] = (f32x4){0.f, 0.f, 0.f, 0.f};

  for (int kt = 0; kt < K / 32; ++kt){
    int kbase = kt * 32 + kgrp * 8;
    bf16x8 bh = *(const bf16x8*)(Wh + (size_t)col * K + kbase);
    bf16x8 bl = *(const bf16x8*)(Wl + (size_t)col * K + kbase);
#pragma unroll
    for (int m = 0; m < MT; ++m){
      size_t ai = (size_t)(mbase + m * 16 + (lane & 15)) * K + kbase;
      bf16x8 ah = *(const bf16x8*)(Xh + ai);
      bf16x8 al = *(const bf16x8*)(Xl + ai);
      acc[m] = __builtin_amdgcn_mfma_f32_16x16x32_bf16(ah, bh, acc[m], 0, 0, 0);
      acc[m] = __builtin_amdgcn_mfma_f32_16x16x32_bf16(ah, bl, acc[m], 0, 0, 0);
      acc[m] = __builtin_amdgcn_mfma_f32_16x16x32_bf16(al, bh, acc[m], 0, 0, 0);
    }
  }

  float asv = aS[col], adv = aD[col];
  int r0 = kgrp * 4;
#pragma unroll
  for (int m = 0; m < MT; ++m){
#pragma unroll
    for (int i = 0; i < 4; ++i){
      int row = mbase + m * 16 + r0 + i;
      float v = acc[m][i];
      Hb[(size_t)row * Nc + col] = f2bf(v);
      float ps = v * asv, pd = v * adv;
      // butterfly over the 16 lanes holding this strip's 16 cols
      ps += __shfl_xor(ps, 1);  pd += __shfl_xor(pd, 1);
      ps += __shfl_xor(ps, 2);  pd += __shfl_xor(pd, 2);
      ps += __shfl_xor(ps, 4);  pd += __shfl_xor(pd, 4);
      ps += __shfl_xor(ps, 8);  pd += __shfl_xor(pd, 8);
      if ((lane & 15) == 0){
        atomicAdd(&alps[row], ps);
        atomicAdd(&alpd[row], pd);
      }
    }
  }
}

// ---------------- per-edge softmax numerator (no max shift needed: |e| small) ----------------
__global__ void w_k(int sel){
  int i = blockIdx.x * blockDim.x + threadIdx.x;
  if (i >= E_TOT) return;
  const float* alps = sel ? g_alps2 : g_alps1;
  const float* alpd = sel ? g_alpd2 : g_alpd1;
  float e = alps[g_srcidx[i]] + alpd[g_dstslot[i]];
  e = (e > 0.f) ? e : NEG_SLOPE * e;
  g_ew[i] = expf(e);
}

// ---------------- aggregation: gather bf16 rows, denom in-loop ----------------
// F/2 threads per node (uint = 2 packed bf16); NPB nodes per 256-thread block.
template<int F, int SEL>
__global__ void agg_k(float* OUT){
  const unsigned int* Hb = (const unsigned int*)(SEL ? g_h2b : g_h1b);
  const float* bias = SEL ? c_b2f : c_b1f;
  const int TPN = F / 2;
  int sub = threadIdx.x / TPN;
  int t   = threadIdx.x % TPN;
  int n   = blockIdx.x * (256 / TPN) + sub;

  int i0 = g_rowstart[n], i1 = g_rowstart[n + 1];
  float a0 = 0.f, a1 = 0.f, den = 0.f;
  for (int i = i0; i < i1; ++i){
    int s = g_srcidx[i];
    float w = g_ew[i];
    den += w;
    unsigned int p = Hb[(size_t)s * TPN + t];
    a0 += w * bf2f((unsigned short)(p & 0xFFFFu));
    a1 += w * bf2f((unsigned short)(p >> 16));
  }
  float inv = 1.f / den;
  float o0 = a0 * inv + bias[2 * t];
  float o1 = a1 * inv + bias[2 * t + 1];
  if (SEL == 0){
    o0 = fmaxf(o0, 0.f); o1 = fmaxf(o1, 0.f);
    unsigned short h0 = f2bf(o0), h1 = f2bf(o1);
    unsigned short l0 = f2bf(o0 - bf2f(h0)), l1 = f2bf(o1 - bf2f(h1));
    ((unsigned int*)g_g1h)[(size_t)n * TPN + t] = (unsigned)h0 | ((unsigned)h1 << 16);
    ((unsigned int*)g_g1l)[(size_t)n * TPN + t] = (unsigned)l0 | ((unsigned)l1 << 16);
  } else {
    float2 o; o.x = o0; o.y = o1;
    ((float2*)OUT)[(size_t)n * TPN + t] = o;
  }
}

extern "C" void kernel_launch(void* const* d_in, const int* in_sizes, int n_in,
                              void* d_out, int out_size, void* d_ws, size_t ws_size,
                              hipStream_t stream){
  (void)in_sizes; (void)n_in; (void)out_size; (void)d_ws; (void)ws_size;
  const void* x  = d_in[0];
  const int*  ei = (const int*)d_in[1];
  float* out = (float*)d_out;

  probe_k<<<1, 64, 0, stream>>>((const unsigned int*)x, ei);
  cvt_x_k<<<(N_NODES * C_IN + 255) / 256, 256, 0, stream>>>(x);
  Ptrs ps;
  ps.p[0] = d_in[2]; ps.p[1] = d_in[3]; ps.p[2] = d_in[4]; ps.p[3] = d_in[5];
  ps.p[4] = d_in[6]; ps.p[5] = d_in[7]; ps.p[6] = d_in[8]; ps.p[7] = d_in[9];
  cvt_w_k<<<dim3((C_IN * C_HID + 255) / 256, 8), 256, 0, stream>>>(ps);

  zero_k<<<(N_NODES + 255) / 256, 256, 0, stream>>>();
  count_k<<<(E_TOT + 255) / 256, 256, 0, stream>>>(ei);
  scanA_k<<<20, 1024, 0, stream>>>();
  scanC_k<<<20, 1024, 0, stream>>>();
  scatter_k<<<(E_TOT + 255) / 256, 256, 0, stream>>>(ei);

  // ---- layer 1 ----
  gemm_k<<<dim3(N_NODES / (16 * MT), C_HID / 64), 256, 0, stream>>>(0);
  w_k<<<(E_TOT + 255) / 256, 256, 0, stream>>>(0);
  agg_k<C_HID, 0><<<N_NODES / 2, 256, 0, stream>>>(nullptr);

  // ---- layer 2 ----
  gemm_k<<<dim3(N_NODES / (16 * MT), C_OUT / 64), 256, 0, stream>>>(1);
  w_k<<<(E_TOT + 255) / 256, 256, 0, stream>>>(1);
  agg_k<C_OUT, 1><<<N_NODES / 4, 256, 0, stream>>>(out);
}

// Round 6
// 289.681 us; speedup vs baseline: 1.5320x; 1.2076x over previous
//
#include <hip/hip_runtime.h>
#include <math.h>

#define N_NODES 20000
#define N_EDGES 320000
#define E_TOT   (N_EDGES + N_NODES)
#define C_IN  256
#define C_HID 256
#define C_OUT 128
#define NEG_SLOPE 0.2f
#define MT 5   // M-tiles (16 rows each) per wave in the MFMA GEMM

typedef __attribute__((ext_vector_type(8))) short bf16x8;
typedef __attribute__((ext_vector_type(4))) float f32x4;

// ---- all scratch in module globals (ws_size unknown; globals are safe) ----
__device__ __align__(16) unsigned short c_xh[(size_t)N_NODES * C_IN];   // x split hi
__device__ __align__(16) unsigned short c_xl[(size_t)N_NODES * C_IN];   // x split lo
// weights stored TRANSPOSED [n][k] so B-fragments are contiguous bf16x8 loads
__device__ __align__(16) unsigned short c_W1h[C_IN * C_HID], c_W1l[C_IN * C_HID];
__device__ __align__(16) unsigned short c_W2h[C_HID * C_OUT], c_W2l[C_HID * C_OUT];
__device__ float c_as1f[C_HID], c_ad1f[C_HID], c_b1f[C_HID];
__device__ float c_as2f[C_OUT], c_ad2f[C_OUT], c_b2f[C_OUT];
__device__ __align__(16) unsigned short g_h1b[(size_t)N_NODES * C_HID]; // h1 bf16
__device__ __align__(16) unsigned short g_g1h[(size_t)N_NODES * C_HID]; // relu(agg1) hi
__device__ __align__(16) unsigned short g_g1l[(size_t)N_NODES * C_HID]; // relu(agg1) lo
__device__ __align__(16) unsigned short g_h2b[(size_t)N_NODES * C_OUT]; // h2 bf16
__device__ float g_alps1[N_NODES], g_alpd1[N_NODES];
__device__ float g_alps2[N_NODES], g_alpd2[N_NODES];
__device__ float g_ew[E_TOT];          // per-edge softmax numerator exp(e)
__device__ int   g_deg[N_NODES];
__device__ int   g_rowstart[N_NODES + 1];
__device__ int   g_cursor[N_NODES];
__device__ int   g_srcidx[E_TOT];
__device__ int   g_dstslot[E_TOT];
__device__ int   g_bsum[20];
__device__ int   g_is64;    // edge_index arrived as raw int64 words
__device__ int   g_isf32;   // float inputs arrived as raw fp32 words

__device__ __forceinline__ float bf2f(unsigned short b){
  unsigned int u = ((unsigned int)b) << 16;
  return __builtin_bit_cast(float, u);
}
__device__ __forceinline__ unsigned short f2bf(float f){
  unsigned int u = __builtin_bit_cast(unsigned int, f);
  u += 0x7fffu + ((u >> 16) & 1u);   // round-to-nearest-even
  return (unsigned short)(u >> 16);
}
__device__ __forceinline__ int clampi(int v){
  v = v < 0 ? 0 : v;
  return v >= N_NODES ? N_NODES - 1 : v;
}
__device__ __forceinline__ void edge_sd(const int* ei, int e, int& s, int& d){
  if (e < N_EDGES){
    if (g_is64){ s = ei[2 * e]; d = ei[2 * (N_EDGES + e)]; }
    else       { s = ei[e];     d = ei[N_EDGES + e]; }
    s = clampi(s); d = clampi(d);
  } else {
    s = d = e - N_EDGES;  // self-loop
  }
}

// ---------------- dtype / layout probes ----------------
__global__ void probe_k(const unsigned int* __restrict__ xw, const int* __restrict__ ei){
  if (threadIdx.x != 0 || blockIdx.x != 0) return;
  int inwin = 0;
  for (int i = 0; i < 256; ++i){
    unsigned int e = (xw[i] >> 7) & 0xFFu;
    if (e >= 0x60u && e <= 0x8Fu) ++inwin;
  }
  g_isf32 = (inwin < 200) ? 1 : 0;   // fp32 low-mantissa bits ~uniform
  int all0 = 1;
  for (int i = 0; i < 64; ++i)
    if (ei[2 * i + 1] != 0){ all0 = 0; break; }
  g_is64 = all0;
}

// ---------------- canonicalize inputs ----------------
__global__ void cvt_x_k(const void* __restrict__ src){
  int i = blockIdx.x * blockDim.x + threadIdx.x;
  if (i >= N_NODES * C_IN) return;
  float f = g_isf32 ? ((const float*)src)[i] : bf2f(((const unsigned short*)src)[i]);
  unsigned short h = f2bf(f);
  c_xh[i] = h;
  c_xl[i] = f2bf(f - bf2f(h));
}

struct Ptrs { const void* p[8]; };

__global__ void cvt_w_k(Ptrs ps){
  // b: 0=W1 1=a_src1 2=a_dst1 3=b1 4=W2 5=a_src2 6=a_dst2 7=b2
  const int sizes[8] = {C_IN * C_HID, C_HID, C_HID, C_HID,
                        C_HID * C_OUT, C_OUT, C_OUT, C_OUT};
  int b = blockIdx.y;
  int i = blockIdx.x * blockDim.x + threadIdx.x;
  if (i >= sizes[b]) return;
  const void* s = ps.p[b];
  float f = g_isf32 ? ((const float*)s)[i] : bf2f(((const unsigned short*)s)[i]);
  if (b == 0){                           // W1 [256][256] -> transposed [n][k]
    int k = i / C_HID, n = i % C_HID;
    unsigned short h = f2bf(f);
    c_W1h[n * C_IN + k] = h;
    c_W1l[n * C_IN + k] = f2bf(f - bf2f(h));
  } else if (b == 4){                    // W2 [256][128] -> transposed [n][k]
    int k = i / C_OUT, n = i % C_OUT;
    unsigned short h = f2bf(f);
    c_W2h[n * C_HID + k] = h;
    c_W2l[n * C_HID + k] = f2bf(f - bf2f(h));
  } else {
    float* vd = (b == 1) ? c_as1f : (b == 2) ? c_ad1f : (b == 3) ? c_b1f
              : (b == 5) ? c_as2f : (b == 6) ? c_ad2f : c_b2f;
    vd[i] = f;
  }
}

// ---------------- graph preprocessing ----------------
__global__ void zero_k(){
  int i = blockIdx.x * blockDim.x + threadIdx.x;
  if (i < N_NODES){
    g_deg[i] = 0;
    g_alps1[i] = 0.f; g_alpd1[i] = 0.f;
    g_alps2[i] = 0.f; g_alpd2[i] = 0.f;
  }
}

__global__ void count_k(const int* __restrict__ ei){
  int e = blockIdx.x * blockDim.x + threadIdx.x;
  if (e >= E_TOT) return;
  int s, d;
  edge_sd(ei, e, s, d);
  atomicAdd(&g_deg[d], 1);
}

// two-phase multi-block exclusive scan of deg[20000]: 20 blocks x 1000
__global__ void scanA_k(){
  __shared__ int s[1024];
  int b = blockIdx.x, t = threadIdx.x;
  int i = b * 1000 + t;
  int v = (t < 1000) ? g_deg[i] : 0;
  s[t] = v;
  __syncthreads();
  for (int off = 1; off < 1024; off <<= 1){
    int x = (t >= off) ? s[t - off] : 0;
    __syncthreads();
    s[t] += x;
    __syncthreads();
  }
  if (t < 1000) g_rowstart[i] = s[t] - v;   // block-local exclusive
  if (t == 1023) g_bsum[b] = s[1023];
}

__global__ void scanC_k(){
  __shared__ int off;
  int b = blockIdx.x, t = threadIdx.x;
  if (t == 0){
    int o = 0;
    for (int j = 0; j < b; ++j) o += g_bsum[j];
    off = o;
  }
  __syncthreads();
  int i = b * 1000 + t;
  if (t < 1000){
    int val = g_rowstart[i] + off;
    g_rowstart[i] = val;
    g_cursor[i]   = val;
  }
  if (b == 0 && t == 0) g_rowstart[N_NODES] = E_TOT;
}

__global__ void scatter_k(const int* __restrict__ ei){
  int e = blockIdx.x * blockDim.x + threadIdx.x;
  if (e >= E_TOT) return;
  int s, d;
  edge_sd(ei, e, s, d);
  int pos = atomicAdd(&g_cursor[d], 1);
  g_srcidx[pos]  = s;
  g_dstslot[pos] = d;
}

// ---------------- split-bf16 MFMA GEMM + fused alpha epilogue ----------------
__global__ void gemm_k(int sel){
  const unsigned short* Xh = sel ? g_g1h : c_xh;
  const unsigned short* Xl = sel ? g_g1l : c_xl;
  const unsigned short* Wh = sel ? c_W2h : c_W1h;   // [n][k]
  const unsigned short* Wl = sel ? c_W2l : c_W1l;
  unsigned short* Hb = sel ? g_h2b : g_h1b;
  float* alps = sel ? g_alps2 : g_alps1;
  float* alpd = sel ? g_alpd2 : g_alpd1;
  const float* aS = sel ? c_as2f : c_as1f;
  const float* aD = sel ? c_ad2f : c_ad1f;
  const int K  = 256;
  const int Nc = sel ? C_OUT : C_HID;

  int wave = (int)(threadIdx.x >> 6);
  int lane = (int)(threadIdx.x & 63);
  int col  = (blockIdx.y * 4 + wave) * 16 + (lane & 15);
  int kgrp = lane >> 4;
  int mbase = blockIdx.x * (16 * MT);

  f32x4 acc[MT];
#pragma unroll
  for (int m = 0; m < MT; ++m) acc[m] = (f32x4){0.f, 0.f, 0.f, 0.f};

  for (int kt = 0; kt < K / 32; ++kt){
    int kbase = kt * 32 + kgrp * 8;
    bf16x8 bh = *(const bf16x8*)(Wh + (size_t)col * K + kbase);
    bf16x8 bl = *(const bf16x8*)(Wl + (size_t)col * K + kbase);
#pragma unroll
    for (int m = 0; m < MT; ++m){
      size_t ai = (size_t)(mbase + m * 16 + (lane & 15)) * K + kbase;
      bf16x8 ah = *(const bf16x8*)(Xh + ai);
      bf16x8 al = *(const bf16x8*)(Xl + ai);
      acc[m] = __builtin_amdgcn_mfma_f32_16x16x32_bf16(ah, bh, acc[m], 0, 0, 0);
      acc[m] = __builtin_amdgcn_mfma_f32_16x16x32_bf16(ah, bl, acc[m], 0, 0, 0);
      acc[m] = __builtin_amdgcn_mfma_f32_16x16x32_bf16(al, bh, acc[m], 0, 0, 0);
    }
  }

  float asv = aS[col], adv = aD[col];
  int r0 = kgrp * 4;
#pragma unroll
  for (int m = 0; m < MT; ++m){
#pragma unroll
    for (int i = 0; i < 4; ++i){
      int row = mbase + m * 16 + r0 + i;
      float v = acc[m][i];
      Hb[(size_t)row * Nc + col] = f2bf(v);
      float ps = v * asv, pd = v * adv;
      ps += __shfl_xor(ps, 1);  pd += __shfl_xor(pd, 1);
      ps += __shfl_xor(ps, 2);  pd += __shfl_xor(pd, 2);
      ps += __shfl_xor(ps, 4);  pd += __shfl_xor(pd, 4);
      ps += __shfl_xor(ps, 8);  pd += __shfl_xor(pd, 8);
      if ((lane & 15) == 0){
        atomicAdd(&alps[row], ps);
        atomicAdd(&alpd[row], pd);
      }
    }
  }
}

// ---------------- per-edge softmax numerator (no max shift: |e| small) ----------------
__global__ void w_k(int sel){
  int i = blockIdx.x * blockDim.x + threadIdx.x;
  if (i >= E_TOT) return;
  const float* alps = sel ? g_alps2 : g_alps1;
  const float* alpd = sel ? g_alpd2 : g_alpd1;
  float e = alps[g_srcidx[i]] + alpd[g_dstslot[i]];
  e = (e > 0.f) ? e : NEG_SLOPE * e;
  g_ew[i] = expf(e);
}

// ---------------- aggregation: one wave per node, edge loop unrolled x4 ----------------
#define ACC4(p, w) { \
  a0 += (w) * bf2f((unsigned short)((p).x & 0xFFFFu)); \
  a1 += (w) * bf2f((unsigned short)((p).x >> 16)); \
  a2 += (w) * bf2f((unsigned short)((p).y & 0xFFFFu)); \
  a3 += (w) * bf2f((unsigned short)((p).y >> 16)); }

#define ACC2(p, w) { \
  a0 += (w) * bf2f((unsigned short)((p) & 0xFFFFu)); \
  a1 += (w) * bf2f((unsigned short)((p) >> 16)); }

template<int F, int SEL>
__global__ void agg_k(float* OUT){
  const unsigned short* Hb = SEL ? g_h2b : g_h1b;
  const float* bias = SEL ? c_b2f : c_b1f;
  int lane = threadIdx.x & 63;
  int n = blockIdx.x * 4 + (threadIdx.x >> 6);
  int i0 = g_rowstart[n], i1 = g_rowstart[n + 1];
  float den = 0.f;

  if constexpr (F == 256){
    const uint2* H2 = (const uint2*)Hb;   // lane owns feats [4*lane, 4*lane+4)
    float a0 = 0.f, a1 = 0.f, a2 = 0.f, a3 = 0.f;
    int i = i0;
    for (; i + 4 <= i1; i += 4){
      int s0 = g_srcidx[i],     s1 = g_srcidx[i + 1];
      int s2 = g_srcidx[i + 2], s3 = g_srcidx[i + 3];
      float w0 = g_ew[i],     w1 = g_ew[i + 1];
      float w2 = g_ew[i + 2], w3 = g_ew[i + 3];
      uint2 p0 = H2[(size_t)s0 * 64 + lane];
      uint2 p1 = H2[(size_t)s1 * 64 + lane];
      uint2 p2 = H2[(size_t)s2 * 64 + lane];
      uint2 p3 = H2[(size_t)s3 * 64 + lane];
      den += (w0 + w1) + (w2 + w3);
      ACC4(p0, w0) ACC4(p1, w1) ACC4(p2, w2) ACC4(p3, w3)
    }
    for (; i < i1; ++i){
      int s = g_srcidx[i];
      float w = g_ew[i];
      uint2 p = H2[(size_t)s * 64 + lane];
      den += w;
      ACC4(p, w)
    }
    float inv = 1.f / den;
    float o0 = a0 * inv + bias[4 * lane];
    float o1 = a1 * inv + bias[4 * lane + 1];
    float o2 = a2 * inv + bias[4 * lane + 2];
    float o3 = a3 * inv + bias[4 * lane + 3];
    if (SEL == 0){
      o0 = fmaxf(o0, 0.f); o1 = fmaxf(o1, 0.f);
      o2 = fmaxf(o2, 0.f); o3 = fmaxf(o3, 0.f);
      unsigned short h0 = f2bf(o0), h1 = f2bf(o1), h2 = f2bf(o2), h3 = f2bf(o3);
      uint2 ph, pl;
      ph.x = (unsigned)h0 | ((unsigned)h1 << 16);
      ph.y = (unsigned)h2 | ((unsigned)h3 << 16);
      pl.x = (unsigned)f2bf(o0 - bf2f(h0)) | ((unsigned)f2bf(o1 - bf2f(h1)) << 16);
      pl.y = (unsigned)f2bf(o2 - bf2f(h2)) | ((unsigned)f2bf(o3 - bf2f(h3)) << 16);
      ((uint2*)g_g1h)[(size_t)n * 64 + lane] = ph;
      ((uint2*)g_g1l)[(size_t)n * 64 + lane] = pl;
    } else {
      float4 o; o.x = o0; o.y = o1; o.z = o2; o.w = o3;
      ((float4*)OUT)[(size_t)n * 64 + lane] = o;
    }
  } else {  // F == 128: lane owns feats [2*lane, 2*lane+2)
    const unsigned int* H1 = (const unsigned int*)Hb;
    float a0 = 0.f, a1 = 0.f;
    int i = i0;
    for (; i + 4 <= i1; i += 4){
      int s0 = g_srcidx[i],     s1 = g_srcidx[i + 1];
      int s2 = g_srcidx[i + 2], s3 = g_srcidx[i + 3];
      float w0 = g_ew[i],     w1 = g_ew[i + 1];
      float w2 = g_ew[i + 2], w3 = g_ew[i + 3];
      unsigned int p0 = H1[(size_t)s0 * 64 + lane];
      unsigned int p1 = H1[(size_t)s1 * 64 + lane];
      unsigned int p2 = H1[(size_t)s2 * 64 + lane];
      unsigned int p3 = H1[(size_t)s3 * 64 + lane];
      den += (w0 + w1) + (w2 + w3);
      ACC2(p0, w0) ACC2(p1, w1) ACC2(p2, w2) ACC2(p3, w3)
    }
    for (; i < i1; ++i){
      int s = g_srcidx[i];
      float w = g_ew[i];
      unsigned int p = H1[(size_t)s * 64 + lane];
      den += w;
      ACC2(p, w)
    }
    float inv = 1.f / den;
    float o0 = a0 * inv + bias[2 * lane];
    float o1 = a1 * inv + bias[2 * lane + 1];
    if (SEL == 0){
      // not used in this config (layer1 is F=256), kept for completeness
      o0 = fmaxf(o0, 0.f); o1 = fmaxf(o1, 0.f);
      unsigned short h0 = f2bf(o0), h1 = f2bf(o1);
      ((unsigned int*)g_g1h)[(size_t)n * 64 + lane] = (unsigned)h0 | ((unsigned)h1 << 16);
      ((unsigned int*)g_g1l)[(size_t)n * 64 + lane] =
        (unsigned)f2bf(o0 - bf2f(h0)) | ((unsigned)f2bf(o1 - bf2f(h1)) << 16);
    } else {
      float2 o; o.x = o0; o.y = o1;
      ((float2*)OUT)[(size_t)n * 64 + lane] = o;
    }
  }
}

extern "C" void kernel_launch(void* const* d_in, const int* in_sizes, int n_in,
                              void* d_out, int out_size, void* d_ws, size_t ws_size,
                              hipStream_t stream){
  (void)in_sizes; (void)n_in; (void)out_size; (void)d_ws; (void)ws_size;
  const void* x  = d_in[0];
  const int*  ei = (const int*)d_in[1];
  float* out = (float*)d_out;

  probe_k<<<1, 64, 0, stream>>>((const unsigned int*)x, ei);
  cvt_x_k<<<(N_NODES * C_IN + 255) / 256, 256, 0, stream>>>(x);
  Ptrs ps;
  ps.p[0] = d_in[2]; ps.p[1] = d_in[3]; ps.p[2] = d_in[4]; ps.p[3] = d_in[5];
  ps.p[4] = d_in[6]; ps.p[5] = d_in[7]; ps.p[6] = d_in[8]; ps.p[7] = d_in[9];
  cvt_w_k<<<dim3((C_IN * C_HID + 255) / 256, 8), 256, 0, stream>>>(ps);

  zero_k<<<(N_NODES + 255) / 256, 256, 0, stream>>>();
  count_k<<<(E_TOT + 255) / 256, 256, 0, stream>>>(ei);
  scanA_k<<<20, 1024, 0, stream>>>();
  scanC_k<<<20, 1024, 0, stream>>>();
  scatter_k<<<(E_TOT + 255) / 256, 256, 0, stream>>>(ei);

  // ---- layer 1 ----
  gemm_k<<<dim3(N_NODES / (16 * MT), C_HID / 64), 256, 0, stream>>>(0);
  w_k<<<(E_TOT + 255) / 256, 256, 0, stream>>>(0);
  agg_k<C_HID, 0><<<N_NODES / 4, 256, 0, stream>>>(nullptr);

  // ---- layer 2 ----
  gemm_k<<<dim3(N_NODES / (16 * MT), C_OUT / 64), 256, 0, stream>>>(1);
  w_k<<<(E_TOT + 255) / 256, 256, 0, stream>>>(1);
  agg_k<C_OUT, 1><<<N_NODES / 4, 256, 0, stream>>>(out);
}

// Round 7
// 243.463 us; speedup vs baseline: 1.8228x; 1.1898x over previous
//
#include <hip/hip_runtime.h>
#include <math.h>

#define N_NODES 20000
#define N_EDGES 320000
#define E_TOT   (N_EDGES + N_NODES)
#define C_IN  256
#define C_HID 256
#define C_OUT 128
#define NEG_SLOPE 0.2f

typedef __attribute__((ext_vector_type(8))) short bf16x8;
typedef __attribute__((ext_vector_type(4))) float f32x4;

// ---- all scratch in module globals (ws_size unknown; globals are safe) ----
__device__ __align__(16) unsigned short c_xh[(size_t)N_NODES * C_IN];   // x split hi
__device__ __align__(16) unsigned short c_xl[(size_t)N_NODES * C_IN];   // x split lo
// weights packed in MFMA-fragment order: idx = ((kt*(Nc/16)+ntile)*64 + kgrp*16+col%16)*8 + k%8
__device__ __align__(16) unsigned short c_W1h[C_IN * C_HID], c_W1l[C_IN * C_HID];
__device__ __align__(16) unsigned short c_W2h[C_HID * C_OUT], c_W2l[C_HID * C_OUT];
__device__ float c_as1f[C_HID], c_ad1f[C_HID], c_b1f[C_HID];
__device__ float c_as2f[C_OUT], c_ad2f[C_OUT], c_b2f[C_OUT];
__device__ __align__(16) unsigned short g_h1b[(size_t)N_NODES * C_HID]; // h1 bf16
__device__ __align__(16) unsigned short g_g1h[(size_t)N_NODES * C_HID]; // relu(agg1) hi
__device__ __align__(16) unsigned short g_g1l[(size_t)N_NODES * C_HID]; // relu(agg1) lo
__device__ __align__(16) unsigned short g_h2b[(size_t)N_NODES * C_OUT]; // h2 bf16
__device__ float g_alps1[N_NODES], g_alpd1[N_NODES];
__device__ float g_alps2[N_NODES], g_alpd2[N_NODES];
__device__ float g_ew[E_TOT];          // per-edge softmax numerator exp(e)
__device__ int   g_deg[N_NODES];
__device__ int   g_rowstart[N_NODES + 1];
__device__ int   g_cursor[N_NODES];
__device__ int   g_srcidx[E_TOT];
__device__ int   g_dstslot[E_TOT];
__device__ int   g_bsum[20];
__device__ int   g_is64;    // edge_index arrived as raw int64 words
__device__ int   g_isf32;   // float inputs arrived as raw fp32 words

__device__ __forceinline__ float bf2f(unsigned short b){
  unsigned int u = ((unsigned int)b) << 16;
  return __builtin_bit_cast(float, u);
}
__device__ __forceinline__ unsigned short f2bf(float f){
  unsigned int u = __builtin_bit_cast(unsigned int, f);
  u += 0x7fffu + ((u >> 16) & 1u);   // round-to-nearest-even
  return (unsigned short)(u >> 16);
}
__device__ __forceinline__ int clampi(int v){
  v = v < 0 ? 0 : v;
  return v >= N_NODES ? N_NODES - 1 : v;
}
__device__ __forceinline__ void edge_sd(const int* ei, int e, int& s, int& d){
  if (e < N_EDGES){
    if (g_is64){ s = ei[2 * e]; d = ei[2 * (N_EDGES + e)]; }
    else       { s = ei[e];     d = ei[N_EDGES + e]; }
    s = clampi(s); d = clampi(d);
  } else {
    s = d = e - N_EDGES;  // self-loop
  }
}

// ---------------- dtype / layout probes ----------------
__global__ void probe_k(const unsigned int* __restrict__ xw, const int* __restrict__ ei){
  if (threadIdx.x != 0 || blockIdx.x != 0) return;
  int inwin = 0;
  for (int i = 0; i < 256; ++i){
    unsigned int e = (xw[i] >> 7) & 0xFFu;
    if (e >= 0x60u && e <= 0x8Fu) ++inwin;
  }
  g_isf32 = (inwin < 200) ? 1 : 0;   // fp32 low-mantissa bits ~uniform
  int all0 = 1;
  for (int i = 0; i < 64; ++i)
    if (ei[2 * i + 1] != 0){ all0 = 0; break; }
  g_is64 = all0;
}

// ---------------- canonicalize inputs ----------------
__global__ void cvt_x_k(const void* __restrict__ src){
  int i = blockIdx.x * blockDim.x + threadIdx.x;
  if (i >= N_NODES * C_IN) return;
  float f = g_isf32 ? ((const float*)src)[i] : bf2f(((const unsigned short*)src)[i]);
  unsigned short h = f2bf(f);
  c_xh[i] = h;
  c_xl[i] = f2bf(f - bf2f(h));
}

struct Ptrs { const void* p[8]; };

// pack (k, n) of a [K][Nc] weight into MFMA B-fragment order
__device__ __forceinline__ int wpack(int k, int n, int Nc){
  return (((k >> 5) * (Nc / 16) + (n >> 4)) * 64 + (((k >> 3) & 3) * 16 + (n & 15))) * 8 + (k & 7);
}

__global__ void cvt_w_k(Ptrs ps){
  // b: 0=W1 1=a_src1 2=a_dst1 3=b1 4=W2 5=a_src2 6=a_dst2 7=b2
  const int sizes[8] = {C_IN * C_HID, C_HID, C_HID, C_HID,
                        C_HID * C_OUT, C_OUT, C_OUT, C_OUT};
  int b = blockIdx.y;
  int i = blockIdx.x * blockDim.x + threadIdx.x;
  if (i >= sizes[b]) return;
  const void* s = ps.p[b];
  float f = g_isf32 ? ((const float*)s)[i] : bf2f(((const unsigned short*)s)[i]);
  if (b == 0){                           // W1[k][n]
    int k = i / C_HID, n = i % C_HID;
    int idx = wpack(k, n, C_HID);
    unsigned short h = f2bf(f);
    c_W1h[idx] = h; c_W1l[idx] = f2bf(f - bf2f(h));
  } else if (b == 4){                    // W2[k][n]
    int k = i / C_OUT, n = i % C_OUT;
    int idx = wpack(k, n, C_OUT);
    unsigned short h = f2bf(f);
    c_W2h[idx] = h; c_W2l[idx] = f2bf(f - bf2f(h));
  } else {
    float* vd = (b == 1) ? c_as1f : (b == 2) ? c_ad1f : (b == 3) ? c_b1f
              : (b == 5) ? c_as2f : (b == 6) ? c_ad2f : c_b2f;
    vd[i] = f;
  }
}

// ---------------- graph preprocessing ----------------
__global__ void zero_k(){
  int i = blockIdx.x * blockDim.x + threadIdx.x;
  if (i < N_NODES){
    g_deg[i] = 0;
    g_alps1[i] = 0.f; g_alpd1[i] = 0.f;
    g_alps2[i] = 0.f; g_alpd2[i] = 0.f;
  }
}

__global__ void count_k(const int* __restrict__ ei){
  int e = blockIdx.x * blockDim.x + threadIdx.x;
  if (e >= E_TOT) return;
  int s, d;
  edge_sd(ei, e, s, d);
  atomicAdd(&g_deg[d], 1);
}

// two-phase multi-block exclusive scan of deg[20000]: 20 blocks x 1000
__global__ void scanA_k(){
  __shared__ int s[1024];
  int b = blockIdx.x, t = threadIdx.x;
  int i = b * 1000 + t;
  int v = (t < 1000) ? g_deg[i] : 0;
  s[t] = v;
  __syncthreads();
  for (int off = 1; off < 1024; off <<= 1){
    int x = (t >= off) ? s[t - off] : 0;
    __syncthreads();
    s[t] += x;
    __syncthreads();
  }
  if (t < 1000) g_rowstart[i] = s[t] - v;   // block-local exclusive
  if (t == 1023) g_bsum[b] = s[1023];
}

__global__ void scanC_k(){
  __shared__ int off;
  int b = blockIdx.x, t = threadIdx.x;
  if (t == 0){
    int o = 0;
    for (int j = 0; j < b; ++j) o += g_bsum[j];
    off = o;
  }
  __syncthreads();
  int i = b * 1000 + t;
  if (t < 1000){
    int val = g_rowstart[i] + off;
    g_rowstart[i] = val;
    g_cursor[i]   = val;
  }
  if (b == 0 && t == 0) g_rowstart[N_NODES] = E_TOT;
}

__global__ void scatter_k(const int* __restrict__ ei){
  int e = blockIdx.x * blockDim.x + threadIdx.x;
  if (e >= E_TOT) return;
  int s, d;
  edge_sd(ei, e, s, d);
  int pos = atomicAdd(&g_cursor[d], 1);
  g_srcidx[pos]  = s;
  g_dstslot[pos] = d;
}

// ---------------- split-bf16 MFMA GEMM + fused alpha epilogue ----------------
// One block = 32 rows x ALL cols. 4 waves split cols; A-frags reused from
// registers across n-tiles (X read once); W packed frag-major (coalesced).
// grid = 625, block 256.  SEL=0: Nc=256, NT=4.  SEL=1: Nc=128, NT=2.
template<int SEL>
__global__ __launch_bounds__(256) void gemm_k(){
  const int Nc = SEL ? C_OUT : C_HID;
  const int NT = SEL ? 2 : 4;
  const unsigned short* Xh = SEL ? g_g1h : c_xh;
  const unsigned short* Xl = SEL ? g_g1l : c_xl;
  const unsigned short* Wh = SEL ? c_W2h : c_W1h;
  const unsigned short* Wl = SEL ? c_W2l : c_W1l;
  unsigned short* Hb = SEL ? g_h2b : g_h1b;
  float* alps = SEL ? g_alps2 : g_alps1;
  float* alpd = SEL ? g_alpd2 : g_alpd1;
  const float* aS = SEL ? c_as2f : c_as1f;
  const float* aD = SEL ? c_ad2f : c_ad1f;

  int wave = (int)(threadIdx.x >> 6);
  int lane = (int)(threadIdx.x & 63);
  int kgrp = lane >> 4, cl = lane & 15;
  int mbase = blockIdx.x * 32;

  f32x4 acc[2][4];
#pragma unroll
  for (int m = 0; m < 2; ++m)
#pragma unroll
    for (int n = 0; n < NT; ++n) acc[m][n] = (f32x4){0.f, 0.f, 0.f, 0.f};

  for (int kt = 0; kt < 8; ++kt){
    int kbase = kt * 32 + kgrp * 8;
    bf16x8 ah[2], al[2];
#pragma unroll
    for (int m = 0; m < 2; ++m){
      size_t ai = (size_t)(mbase + m * 16 + cl) * 256 + kbase;
      ah[m] = *(const bf16x8*)(Xh + ai);
      al[m] = *(const bf16x8*)(Xl + ai);
    }
#pragma unroll
    for (int nn = 0; nn < NT; ++nn){
      int nt = wave * NT + nn;
      size_t wi = ((size_t)(kt * (Nc / 16) + nt) * 64 + lane) * 8;
      bf16x8 bh = *(const bf16x8*)(Wh + wi);
      bf16x8 bl = *(const bf16x8*)(Wl + wi);
#pragma unroll
      for (int m = 0; m < 2; ++m){
        acc[m][nn] = __builtin_amdgcn_mfma_f32_16x16x32_bf16(ah[m], bh, acc[m][nn], 0, 0, 0);
        acc[m][nn] = __builtin_amdgcn_mfma_f32_16x16x32_bf16(ah[m], bl, acc[m][nn], 0, 0, 0);
        acc[m][nn] = __builtin_amdgcn_mfma_f32_16x16x32_bf16(al[m], bh, acc[m][nn], 0, 0, 0);
      }
    }
  }

  float asv[4], adv[4];
#pragma unroll
  for (int nn = 0; nn < NT; ++nn){
    int col = (wave * NT + nn) * 16 + cl;
    asv[nn] = aS[col]; adv[nn] = aD[col];
  }
#pragma unroll
  for (int m = 0; m < 2; ++m){
#pragma unroll
    for (int i = 0; i < 4; ++i){
      int row = mbase + m * 16 + kgrp * 4 + i;
      float ps = 0.f, pd = 0.f;
#pragma unroll
      for (int nn = 0; nn < NT; ++nn){
        int col = (wave * NT + nn) * 16 + cl;
        float v = acc[m][nn][i];
        Hb[(size_t)row * Nc + col] = f2bf(v);
        ps += v * asv[nn]; pd += v * adv[nn];
      }
      ps += __shfl_xor(ps, 1);  pd += __shfl_xor(pd, 1);
      ps += __shfl_xor(ps, 2);  pd += __shfl_xor(pd, 2);
      ps += __shfl_xor(ps, 4);  pd += __shfl_xor(pd, 4);
      ps += __shfl_xor(ps, 8);  pd += __shfl_xor(pd, 8);
      if (cl == 0){
        atomicAdd(&alps[row], ps);
        atomicAdd(&alpd[row], pd);
      }
    }
  }
}

// ---------------- per-edge softmax numerator (no max shift: |e| small) ----------------
__global__ void w_k(int sel){
  int i = blockIdx.x * blockDim.x + threadIdx.x;
  if (i >= E_TOT) return;
  const float* alps = sel ? g_alps2 : g_alps1;
  const float* alpd = sel ? g_alpd2 : g_alpd1;
  float e = alps[g_srcidx[i]] + alpd[g_dstslot[i]];
  e = (e > 0.f) ? e : NEG_SLOPE * e;
  g_ew[i] = expf(e);
}

// ---------------- aggregation: one wave per node, edge loop unrolled x4 ----------------
#define ACC4(p, w) { \
  a0 += (w) * bf2f((unsigned short)((p).x & 0xFFFFu)); \
  a1 += (w) * bf2f((unsigned short)((p).x >> 16)); \
  a2 += (w) * bf2f((unsigned short)((p).y & 0xFFFFu)); \
  a3 += (w) * bf2f((unsigned short)((p).y >> 16)); }

#define ACC2(p, w) { \
  a0 += (w) * bf2f((unsigned short)((p) & 0xFFFFu)); \
  a1 += (w) * bf2f((unsigned short)((p) >> 16)); }

template<int F, int SEL>
__global__ void agg_k(float* OUT){
  const unsigned short* Hb = SEL ? g_h2b : g_h1b;
  const float* bias = SEL ? c_b2f : c_b1f;
  int lane = threadIdx.x & 63;
  int n = blockIdx.x * 4 + (threadIdx.x >> 6);
  int i0 = g_rowstart[n], i1 = g_rowstart[n + 1];
  float den = 0.f;

  if constexpr (F == 256){
    const uint2* H2 = (const uint2*)Hb;   // lane owns feats [4*lane, 4*lane+4)
    float a0 = 0.f, a1 = 0.f, a2 = 0.f, a3 = 0.f;
    int i = i0;
    for (; i + 4 <= i1; i += 4){
      int s0 = g_srcidx[i],     s1 = g_srcidx[i + 1];
      int s2 = g_srcidx[i + 2], s3 = g_srcidx[i + 3];
      float w0 = g_ew[i],     w1 = g_ew[i + 1];
      float w2 = g_ew[i + 2], w3 = g_ew[i + 3];
      uint2 p0 = H2[(size_t)s0 * 64 + lane];
      uint2 p1 = H2[(size_t)s1 * 64 + lane];
      uint2 p2 = H2[(size_t)s2 * 64 + lane];
      uint2 p3 = H2[(size_t)s3 * 64 + lane];
      den += (w0 + w1) + (w2 + w3);
      ACC4(p0, w0) ACC4(p1, w1) ACC4(p2, w2) ACC4(p3, w3)
    }
    for (; i < i1; ++i){
      int s = g_srcidx[i];
      float w = g_ew[i];
      uint2 p = H2[(size_t)s * 64 + lane];
      den += w;
      ACC4(p, w)
    }
    float inv = 1.f / den;
    float o0 = a0 * inv + bias[4 * lane];
    float o1 = a1 * inv + bias[4 * lane + 1];
    float o2 = a2 * inv + bias[4 * lane + 2];
    float o3 = a3 * inv + bias[4 * lane + 3];
    if (SEL == 0){
      o0 = fmaxf(o0, 0.f); o1 = fmaxf(o1, 0.f);
      o2 = fmaxf(o2, 0.f); o3 = fmaxf(o3, 0.f);
      unsigned short h0 = f2bf(o0), h1 = f2bf(o1), h2 = f2bf(o2), h3 = f2bf(o3);
      uint2 ph, pl;
      ph.x = (unsigned)h0 | ((unsigned)h1 << 16);
      ph.y = (unsigned)h2 | ((unsigned)h3 << 16);
      pl.x = (unsigned)f2bf(o0 - bf2f(h0)) | ((unsigned)f2bf(o1 - bf2f(h1)) << 16);
      pl.y = (unsigned)f2bf(o2 - bf2f(h2)) | ((unsigned)f2bf(o3 - bf2f(h3)) << 16);
      ((uint2*)g_g1h)[(size_t)n * 64 + lane] = ph;
      ((uint2*)g_g1l)[(size_t)n * 64 + lane] = pl;
    } else {
      float4 o; o.x = o0; o.y = o1; o.z = o2; o.w = o3;
      ((float4*)OUT)[(size_t)n * 64 + lane] = o;
    }
  } else {  // F == 128: lane owns feats [2*lane, 2*lane+2)
    const unsigned int* H1 = (const unsigned int*)Hb;
    float a0 = 0.f, a1 = 0.f;
    int i = i0;
    for (; i + 4 <= i1; i += 4){
      int s0 = g_srcidx[i],     s1 = g_srcidx[i + 1];
      int s2 = g_srcidx[i + 2], s3 = g_srcidx[i + 3];
      float w0 = g_ew[i],     w1 = g_ew[i + 1];
      float w2 = g_ew[i + 2], w3 = g_ew[i + 3];
      unsigned int p0 = H1[(size_t)s0 * 64 + lane];
      unsigned int p1 = H1[(size_t)s1 * 64 + lane];
      unsigned int p2 = H1[(size_t)s2 * 64 + lane];
      unsigned int p3 = H1[(size_t)s3 * 64 + lane];
      den += (w0 + w1) + (w2 + w3);
      ACC2(p0, w0) ACC2(p1, w1) ACC2(p2, w2) ACC2(p3, w3)
    }
    for (; i < i1; ++i){
      int s = g_srcidx[i];
      float w = g_ew[i];
      unsigned int p = H1[(size_t)s * 64 + lane];
      den += w;
      ACC2(p, w)
    }
    float inv = 1.f / den;
    float o0 = a0 * inv + bias[2 * lane];
    float o1 = a1 * inv + bias[2 * lane + 1];
    if (SEL == 0){
      o0 = fmaxf(o0, 0.f); o1 = fmaxf(o1, 0.f);
      unsigned short h0 = f2bf(o0), h1 = f2bf(o1);
      ((unsigned int*)g_g1h)[(size_t)n * 64 + lane] = (unsigned)h0 | ((unsigned)h1 << 16);
      ((unsigned int*)g_g1l)[(size_t)n * 64 + lane] =
        (unsigned)f2bf(o0 - bf2f(h0)) | ((unsigned)f2bf(o1 - bf2f(h1)) << 16);
    } else {
      float2 o; o.x = o0; o.y = o1;
      ((float2*)OUT)[(size_t)n * 64 + lane] = o;
    }
  }
}

extern "C" void kernel_launch(void* const* d_in, const int* in_sizes, int n_in,
                              void* d_out, int out_size, void* d_ws, size_t ws_size,
                              hipStream_t stream){
  (void)in_sizes; (void)n_in; (void)out_size; (void)d_ws; (void)ws_size;
  const void* x  = d_in[0];
  const int*  ei = (const int*)d_in[1];
  float* out = (float*)d_out;

  probe_k<<<1, 64, 0, stream>>>((const unsigned int*)x, ei);
  cvt_x_k<<<(N_NODES * C_IN + 255) / 256, 256, 0, stream>>>(x);
  Ptrs ps;
  ps.p[0] = d_in[2]; ps.p[1] = d_in[3]; ps.p[2] = d_in[4]; ps.p[3] = d_in[5];
  ps.p[4] = d_in[6]; ps.p[5] = d_in[7]; ps.p[6] = d_in[8]; ps.p[7] = d_in[9];
  cvt_w_k<<<dim3((C_IN * C_HID + 255) / 256, 8), 256, 0, stream>>>(ps);

  zero_k<<<(N_NODES + 255) / 256, 256, 0, stream>>>();
  count_k<<<(E_TOT + 255) / 256, 256, 0, stream>>>(ei);
  scanA_k<<<20, 1024, 0, stream>>>();
  scanC_k<<<20, 1024, 0, stream>>>();
  scatter_k<<<(E_TOT + 255) / 256, 256, 0, stream>>>(ei);

  // ---- layer 1 ----
  gemm_k<0><<<N_NODES / 32, 256, 0, stream>>>();
  w_k<<<(E_TOT + 255) / 256, 256, 0, stream>>>(0);
  agg_k<C_HID, 0><<<N_NODES / 4, 256, 0, stream>>>(nullptr);

  // ---- layer 2 ----
  gemm_k<1><<<N_NODES / 32, 256, 0, stream>>>();
  w_k<<<(E_TOT + 255) / 256, 256, 0, stream>>>(1);
  agg_k<C_OUT, 1><<<N_NODES / 4, 256, 0, stream>>>(out);
}

// Round 8
// 216.838 us; speedup vs baseline: 2.0466x; 1.1228x over previous
//
#include <hip/hip_runtime.h>
#include <math.h>

#define N_NODES 20000
#define N_EDGES 320000
#define E_TOT   (N_EDGES + N_NODES)
#define C_IN  256
#define C_HID 256
#define C_OUT 128
#define NEG_SLOPE 0.2f

typedef __attribute__((ext_vector_type(8))) short bf16x8;
typedef __attribute__((ext_vector_type(4))) float f32x4;

// ---- all scratch in module globals (ws_size unknown; globals are safe) ----
// weights packed in MFMA-fragment order: idx = ((kt*(Nc/16)+ntile)*64 + kgrp*16+col%16)*8 + k%8
__device__ __align__(16) unsigned short c_W1h[C_IN * C_HID], c_W1l[C_IN * C_HID];
__device__ __align__(16) unsigned short c_W2h[C_HID * C_OUT], c_W2l[C_HID * C_OUT];
__device__ float c_as1f[C_HID], c_ad1f[C_HID], c_b1f[C_HID];
__device__ float c_as2f[C_OUT], c_ad2f[C_OUT], c_b2f[C_OUT];
__device__ __align__(16) unsigned short g_h1b[(size_t)N_NODES * C_HID]; // h1 bf16
__device__ __align__(16) unsigned short g_g1h[(size_t)N_NODES * C_HID]; // relu(agg1) hi
__device__ __align__(16) unsigned short g_g1l[(size_t)N_NODES * C_HID]; // relu(agg1) lo
__device__ __align__(16) unsigned short g_h2b[(size_t)N_NODES * C_OUT]; // h2 bf16
__device__ float g_alps1[N_NODES], g_alpd1[N_NODES];
__device__ float g_alps2[N_NODES], g_alpd2[N_NODES];
__device__ int   g_deg[N_NODES];
__device__ int   g_rowstart[N_NODES + 1];
__device__ int   g_cursor[N_NODES];
__device__ int   g_srcidx[E_TOT];
__device__ int   g_bsum[20];
__device__ int   g_is64;    // edge_index arrived as raw int64 words
__device__ int   g_isf32;   // float inputs arrived as raw fp32 words

__device__ __forceinline__ float bf2f(unsigned short b){
  unsigned int u = ((unsigned int)b) << 16;
  return __builtin_bit_cast(float, u);
}
__device__ __forceinline__ unsigned short f2bf(float f){
  unsigned int u = __builtin_bit_cast(unsigned int, f);
  u += 0x7fffu + ((u >> 16) & 1u);   // round-to-nearest-even
  return (unsigned short)(u >> 16);
}
__device__ __forceinline__ int clampi(int v){
  v = v < 0 ? 0 : v;
  return v >= N_NODES ? N_NODES - 1 : v;
}
__device__ __forceinline__ void edge_sd(const int* ei, int e, int& s, int& d){
  if (e < N_EDGES){
    if (g_is64){ s = ei[2 * e]; d = ei[2 * (N_EDGES + e)]; }
    else       { s = ei[e];     d = ei[N_EDGES + e]; }
    s = clampi(s); d = clampi(d);
  } else {
    s = d = e - N_EDGES;  // self-loop
  }
}

// ---------------- probes + zero init (fused) ----------------
__global__ void probe_zero_k(const unsigned int* __restrict__ xw, const int* __restrict__ ei){
  int i = blockIdx.x * blockDim.x + threadIdx.x;
  if (i < N_NODES){
    g_deg[i] = 0;
    g_alps1[i] = 0.f; g_alpd1[i] = 0.f;
    g_alps2[i] = 0.f; g_alpd2[i] = 0.f;
  }
  if (blockIdx.x == 0 && threadIdx.x == 0){
    // bf16-packed: low 16 bits are N(0,1) bf16 -> exponent in narrow window.
    // fp32: low bits ~uniform mantissa (~19% in-window).
    int inwin = 0;
    for (int j = 0; j < 256; ++j){
      unsigned int e = (xw[j] >> 7) & 0xFFu;
      if (e >= 0x60u && e <= 0x8Fu) ++inwin;
    }
    g_isf32 = (inwin < 200) ? 1 : 0;
    int all0 = 1;
    for (int j = 0; j < 64; ++j)
      if (ei[2 * j + 1] != 0){ all0 = 0; break; }
    g_is64 = all0;
  }
}

struct Ptrs { const void* p[8]; };

// pack (k, n) of a [K][Nc] weight into MFMA B-fragment order
__device__ __forceinline__ int wpack(int k, int n, int Nc){
  return (((k >> 5) * (Nc / 16) + (n >> 4)) * 64 + (((k >> 3) & 3) * 16 + (n & 15))) * 8 + (k & 7);
}

__global__ void cvt_w_k(Ptrs ps){
  // b: 0=W1 1=a_src1 2=a_dst1 3=b1 4=W2 5=a_src2 6=a_dst2 7=b2
  const int sizes[8] = {C_IN * C_HID, C_HID, C_HID, C_HID,
                        C_HID * C_OUT, C_OUT, C_OUT, C_OUT};
  int b = blockIdx.y;
  int i = blockIdx.x * blockDim.x + threadIdx.x;
  if (i >= sizes[b]) return;
  const void* s = ps.p[b];
  float f = g_isf32 ? ((const float*)s)[i] : bf2f(((const unsigned short*)s)[i]);
  if (b == 0){                           // W1[k][n]
    int k = i / C_HID, n = i % C_HID;
    int idx = wpack(k, n, C_HID);
    unsigned short h = f2bf(f);
    c_W1h[idx] = h; c_W1l[idx] = f2bf(f - bf2f(h));
  } else if (b == 4){                    // W2[k][n]
    int k = i / C_OUT, n = i % C_OUT;
    int idx = wpack(k, n, C_OUT);
    unsigned short h = f2bf(f);
    c_W2h[idx] = h; c_W2l[idx] = f2bf(f - bf2f(h));
  } else {
    float* vd = (b == 1) ? c_as1f : (b == 2) ? c_ad1f : (b == 3) ? c_b1f
              : (b == 5) ? c_as2f : (b == 6) ? c_ad2f : c_b2f;
    vd[i] = f;
  }
}

// ---------------- graph preprocessing ----------------
__global__ void count_k(const int* __restrict__ ei){
  int e = blockIdx.x * blockDim.x + threadIdx.x;
  if (e >= E_TOT) return;
  int s, d;
  edge_sd(ei, e, s, d);
  atomicAdd(&g_deg[d], 1);
}

// two-phase multi-block exclusive scan of deg[20000]: 20 blocks x 1000
__global__ void scanA_k(){
  __shared__ int s[1024];
  int b = blockIdx.x, t = threadIdx.x;
  int i = b * 1000 + t;
  int v = (t < 1000) ? g_deg[i] : 0;
  s[t] = v;
  __syncthreads();
  for (int off = 1; off < 1024; off <<= 1){
    int x = (t >= off) ? s[t - off] : 0;
    __syncthreads();
    s[t] += x;
    __syncthreads();
  }
  if (t < 1000) g_rowstart[i] = s[t] - v;   // block-local exclusive
  if (t == 1023) g_bsum[b] = s[1023];
}

__global__ void scanC_k(){
  __shared__ int off;
  int b = blockIdx.x, t = threadIdx.x;
  if (t == 0){
    int o = 0;
    for (int j = 0; j < b; ++j) o += g_bsum[j];
    off = o;
  }
  __syncthreads();
  int i = b * 1000 + t;
  if (t < 1000){
    int val = g_rowstart[i] + off;
    g_rowstart[i] = val;
    g_cursor[i]   = val;
  }
  if (b == 0 && t == 0) g_rowstart[N_NODES] = E_TOT;
}

__global__ void scatter_k(const int* __restrict__ ei){
  int e = blockIdx.x * blockDim.x + threadIdx.x;
  if (e >= E_TOT) return;
  int s, d;
  edge_sd(ei, e, s, d);
  int pos = atomicAdd(&g_cursor[d], 1);
  g_srcidx[pos] = s;
}

// ---------------- split-bf16 MFMA GEMM + fused alpha epilogue ----------------
// One block = 32 rows x ALL cols. 4 waves split cols; A-frags reused from
// registers across n-tiles; W packed frag-major (coalesced).
// SEL=0 reads raw x (fp32 or bf16, split on the fly); SEL=1 reads split g1.
template<int SEL>
__global__ __launch_bounds__(256) void gemm_k(const void* __restrict__ xsrc){
  const int Nc = SEL ? C_OUT : C_HID;
  const int NT = SEL ? 2 : 4;
  const unsigned short* Wh = SEL ? c_W2h : c_W1h;
  const unsigned short* Wl = SEL ? c_W2l : c_W1l;
  unsigned short* Hb = SEL ? g_h2b : g_h1b;
  float* alps = SEL ? g_alps2 : g_alps1;
  float* alpd = SEL ? g_alpd2 : g_alpd1;
  const float* aS = SEL ? c_as2f : c_as1f;
  const float* aD = SEL ? c_ad2f : c_ad1f;
  const bool isf32 = (SEL == 0) && (g_isf32 != 0);

  int wave = (int)(threadIdx.x >> 6);
  int lane = (int)(threadIdx.x & 63);
  int kgrp = lane >> 4, cl = lane & 15;
  int mbase = blockIdx.x * 32;

  f32x4 acc[2][4];
#pragma unroll
  for (int m = 0; m < 2; ++m)
#pragma unroll
    for (int n = 0; n < NT; ++n) acc[m][n] = (f32x4){0.f, 0.f, 0.f, 0.f};

  for (int kt = 0; kt < 8; ++kt){
    int kbase = kt * 32 + kgrp * 8;
    bf16x8 ah[2], al[2];
    if (SEL == 1){
#pragma unroll
      for (int m = 0; m < 2; ++m){
        size_t ai = (size_t)(mbase + m * 16 + cl) * 256 + kbase;
        ah[m] = *(const bf16x8*)(g_g1h + ai);
        al[m] = *(const bf16x8*)(g_g1l + ai);
      }
    } else if (isf32){
      const float* Xf = (const float*)xsrc;
#pragma unroll
      for (int m = 0; m < 2; ++m){
        const float4* xp = (const float4*)(Xf + (size_t)(mbase + m * 16 + cl) * 256 + kbase);
        float4 v0 = xp[0], v1 = xp[1];
        float vals[8] = {v0.x, v0.y, v0.z, v0.w, v1.x, v1.y, v1.z, v1.w};
#pragma unroll
        for (int j = 0; j < 8; ++j){
          unsigned short h = f2bf(vals[j]);
          ah[m][j] = (short)h;
          al[m][j] = (short)f2bf(vals[j] - bf2f(h));
        }
      }
    } else {  // bf16 input: lo part is zero
      const unsigned short* Xb = (const unsigned short*)xsrc;
#pragma unroll
      for (int m = 0; m < 2; ++m){
        ah[m] = *(const bf16x8*)(Xb + (size_t)(mbase + m * 16 + cl) * 256 + kbase);
        al[m] = (bf16x8){0,0,0,0,0,0,0,0};
      }
    }
#pragma unroll
    for (int nn = 0; nn < NT; ++nn){
      int nt = wave * NT + nn;
      size_t wi = ((size_t)(kt * (Nc / 16) + nt) * 64 + lane) * 8;
      bf16x8 bh = *(const bf16x8*)(Wh + wi);
      bf16x8 bl = *(const bf16x8*)(Wl + wi);
#pragma unroll
      for (int m = 0; m < 2; ++m){
        acc[m][nn] = __builtin_amdgcn_mfma_f32_16x16x32_bf16(ah[m], bh, acc[m][nn], 0, 0, 0);
        acc[m][nn] = __builtin_amdgcn_mfma_f32_16x16x32_bf16(ah[m], bl, acc[m][nn], 0, 0, 0);
        acc[m][nn] = __builtin_amdgcn_mfma_f32_16x16x32_bf16(al[m], bh, acc[m][nn], 0, 0, 0);
      }
    }
  }

  float asv[4], adv[4];
#pragma unroll
  for (int nn = 0; nn < NT; ++nn){
    int col = (wave * NT + nn) * 16 + cl;
    asv[nn] = aS[col]; adv[nn] = aD[col];
  }
#pragma unroll
  for (int m = 0; m < 2; ++m){
#pragma unroll
    for (int i = 0; i < 4; ++i){
      int row = mbase + m * 16 + kgrp * 4 + i;
      float ps = 0.f, pd = 0.f;
#pragma unroll
      for (int nn = 0; nn < NT; ++nn){
        int col = (wave * NT + nn) * 16 + cl;
        float v = acc[m][nn][i];
        Hb[(size_t)row * Nc + col] = f2bf(v);
        ps += v * asv[nn]; pd += v * adv[nn];
      }
      ps += __shfl_xor(ps, 1);  pd += __shfl_xor(pd, 1);
      ps += __shfl_xor(ps, 2);  pd += __shfl_xor(pd, 2);
      ps += __shfl_xor(ps, 4);  pd += __shfl_xor(pd, 4);
      ps += __shfl_xor(ps, 8);  pd += __shfl_xor(pd, 8);
      if (cl == 0){
        atomicAdd(&alps[row], ps);
        atomicAdd(&alpd[row], pd);
      }
    }
  }
}

// ---------------- fused softmax + aggregation: one wave per node ----------------
// Chunk 64 edges: lane j loads srcidx (coalesced) + computes exp once; then
// the accumulate loop broadcasts (s,w) via shfl (readlane) - no per-edge
// memory on the address chain.  Gathers issued 4 deep for MLP.
#define ACC4(p, w) { \
  a0 += (w) * bf2f((unsigned short)((p).x & 0xFFFFu)); \
  a1 += (w) * bf2f((unsigned short)((p).x >> 16)); \
  a2 += (w) * bf2f((unsigned short)((p).y & 0xFFFFu)); \
  a3 += (w) * bf2f((unsigned short)((p).y >> 16)); }

#define ACC2(p, w) { \
  a0 += (w) * bf2f((unsigned short)((p) & 0xFFFFu)); \
  a1 += (w) * bf2f((unsigned short)((p) >> 16)); }

template<int F, int SEL>
__global__ void agg_k(float* OUT){
  const unsigned short* Hb = SEL ? g_h2b : g_h1b;
  const float* bias = SEL ? c_b2f : c_b1f;
  const float* alps = SEL ? g_alps2 : g_alps1;
  const float* alpd = SEL ? g_alpd2 : g_alpd1;
  int lane = threadIdx.x & 63;
  int n = blockIdx.x * 4 + (threadIdx.x >> 6);
  int i0 = g_rowstart[n], i1 = g_rowstart[n + 1];
  float adn = alpd[n];
  float dpart = 0.f;
  float a0 = 0.f, a1 = 0.f, a2 = 0.f, a3 = 0.f;
  const uint2* H2 = (const uint2*)Hb;          // F=256: lane owns 4 feats
  const unsigned int* H1 = (const unsigned int*)Hb; // F=128: lane owns 2 feats

  for (int base = i0; base < i1; base += 64){
    int nv = i1 - base; if (nv > 64) nv = 64;
    int sv = 0; float wv = 0.f;
    if (lane < nv){
      sv = g_srcidx[base + lane];
      float e = alps[sv] + adn;
      e = (e > 0.f) ? e : NEG_SLOPE * e;
      wv = __expf(e);
    }
    dpart += wv;
    int j = 0;
    for (; j + 4 <= nv; j += 4){
      int s0 = __shfl(sv, j),     s1 = __shfl(sv, j + 1);
      int s2 = __shfl(sv, j + 2), s3 = __shfl(sv, j + 3);
      float w0 = __shfl(wv, j),     w1 = __shfl(wv, j + 1);
      float w2 = __shfl(wv, j + 2), w3 = __shfl(wv, j + 3);
      if constexpr (F == 256){
        uint2 p0 = H2[(size_t)s0 * 64 + lane];
        uint2 p1 = H2[(size_t)s1 * 64 + lane];
        uint2 p2 = H2[(size_t)s2 * 64 + lane];
        uint2 p3 = H2[(size_t)s3 * 64 + lane];
        ACC4(p0, w0) ACC4(p1, w1) ACC4(p2, w2) ACC4(p3, w3)
      } else {
        unsigned int p0 = H1[(size_t)s0 * 64 + lane];
        unsigned int p1 = H1[(size_t)s1 * 64 + lane];
        unsigned int p2 = H1[(size_t)s2 * 64 + lane];
        unsigned int p3 = H1[(size_t)s3 * 64 + lane];
        ACC2(p0, w0) ACC2(p1, w1) ACC2(p2, w2) ACC2(p3, w3)
      }
    }
    for (; j < nv; ++j){
      int s = __shfl(sv, j);
      float w = __shfl(wv, j);
      if constexpr (F == 256){
        uint2 p = H2[(size_t)s * 64 + lane];
        ACC4(p, w)
      } else {
        unsigned int p = H1[(size_t)s * 64 + lane];
        ACC2(p, w)
      }
    }
  }

  float den = dpart;
#pragma unroll
  for (int o = 32; o > 0; o >>= 1) den += __shfl_xor(den, o, 64);
  float inv = 1.f / den;

  if constexpr (F == 256){
    float o0 = a0 * inv + bias[4 * lane];
    float o1 = a1 * inv + bias[4 * lane + 1];
    float o2 = a2 * inv + bias[4 * lane + 2];
    float o3 = a3 * inv + bias[4 * lane + 3];
    if (SEL == 0){
      o0 = fmaxf(o0, 0.f); o1 = fmaxf(o1, 0.f);
      o2 = fmaxf(o2, 0.f); o3 = fmaxf(o3, 0.f);
      unsigned short h0 = f2bf(o0), h1 = f2bf(o1), h2 = f2bf(o2), h3 = f2bf(o3);
      uint2 ph, pl;
      ph.x = (unsigned)h0 | ((unsigned)h1 << 16);
      ph.y = (unsigned)h2 | ((unsigned)h3 << 16);
      pl.x = (unsigned)f2bf(o0 - bf2f(h0)) | ((unsigned)f2bf(o1 - bf2f(h1)) << 16);
      pl.y = (unsigned)f2bf(o2 - bf2f(h2)) | ((unsigned)f2bf(o3 - bf2f(h3)) << 16);
      ((uint2*)g_g1h)[(size_t)n * 64 + lane] = ph;
      ((uint2*)g_g1l)[(size_t)n * 64 + lane] = pl;
    } else {
      float4 o; o.x = o0; o.y = o1; o.z = o2; o.w = o3;
      ((float4*)OUT)[(size_t)n * 64 + lane] = o;
    }
  } else {
    float o0 = a0 * inv + bias[2 * lane];
    float o1 = a1 * inv + bias[2 * lane + 1];
    if (SEL == 0){
      o0 = fmaxf(o0, 0.f); o1 = fmaxf(o1, 0.f);
      unsigned short h0 = f2bf(o0), h1 = f2bf(o1);
      ((unsigned int*)g_g1h)[(size_t)n * 64 + lane] = (unsigned)h0 | ((unsigned)h1 << 16);
      ((unsigned int*)g_g1l)[(size_t)n * 64 + lane] =
        (unsigned)f2bf(o0 - bf2f(h0)) | ((unsigned)f2bf(o1 - bf2f(h1)) << 16);
    } else {
      float2 o; o.x = o0; o.y = o1;
      ((float2*)OUT)[(size_t)n * 64 + lane] = o;
    }
  }
}

extern "C" void kernel_launch(void* const* d_in, const int* in_sizes, int n_in,
                              void* d_out, int out_size, void* d_ws, size_t ws_size,
                              hipStream_t stream){
  (void)in_sizes; (void)n_in; (void)out_size; (void)d_ws; (void)ws_size;
  const void* x  = d_in[0];
  const int*  ei = (const int*)d_in[1];
  float* out = (float*)d_out;

  probe_zero_k<<<(N_NODES + 255) / 256, 256, 0, stream>>>((const unsigned int*)x, ei);
  Ptrs ps;
  ps.p[0] = d_in[2]; ps.p[1] = d_in[3]; ps.p[2] = d_in[4]; ps.p[3] = d_in[5];
  ps.p[4] = d_in[6]; ps.p[5] = d_in[7]; ps.p[6] = d_in[8]; ps.p[7] = d_in[9];
  cvt_w_k<<<dim3((C_IN * C_HID + 255) / 256, 8), 256, 0, stream>>>(ps);

  count_k<<<(E_TOT + 255) / 256, 256, 0, stream>>>(ei);
  scanA_k<<<20, 1024, 0, stream>>>();
  scanC_k<<<20, 1024, 0, stream>>>();
  scatter_k<<<(E_TOT + 255) / 256, 256, 0, stream>>>(ei);

  // ---- layer 1 ----
  gemm_k<0><<<N_NODES / 32, 256, 0, stream>>>(x);
  agg_k<C_HID, 0><<<N_NODES / 4, 256, 0, stream>>>(nullptr);

  // ---- layer 2 ----
  gemm_k<1><<<N_NODES / 32, 256, 0, stream>>>(nullptr);
  agg_k<C_OUT, 1><<<N_NODES / 4, 256, 0, stream>>>(out);
}